// Round 4
// baseline (227.478 us; speedup 1.0000x reference)
//
#include <hip/hip_runtime.h>
#include <math.h>

#define NQ 6
#define SDIM 64
#define NLAYERS 3
#define QBATCH 262144
#define NGATES (NLAYERS * NQ)

// ---------------------------------------------------------------------------
// Compile-time basis->register permutation tables.
// The CX chain (c=q, t=q+1, q=0..4) is a fixed permutation of basis indices:
//   s_after[i] = s_before[g(i)],  g = f_0∘f_1∘f_2∘f_3∘f_4,
//   f_c(i) = i ^ (((i>>c)&1)<<(c+1)).
// Registers hold the post-encoding layout (identity). After l+1 chains, basis
// index i lives in register g^(l+1)(i). Gates address registers through these
// tables — the CX gates emit ZERO instructions and cause zero register churn.
// ---------------------------------------------------------------------------
struct Perm { int p[SDIM]; };
static constexpr Perm make_perm(int reps) {
    Perm P{};
    for (int i = 0; i < SDIM; ++i) {
        int j = i;
        for (int r = 0; r < reps; ++r)
            for (int c = NQ - 2; c >= 0; --c)
                j ^= ((j >> c) & 1) << (c + 1);
        P.p[i] = j;
    }
    return P;
}
__device__ constexpr Perm PERM_TAB[NLAYERS] = {
    make_perm(1), make_perm(2), make_perm(3)
};

// --- Kernel 1: precompute the 18 fused variational gates (RZ*RY*RX), shared
// across the whole batch, into d_ws. One wave, runs once per call. ---
__global__ void gate_prep_kernel(const float* __restrict__ qw,
                                 float* __restrict__ gates) {
    const int g = threadIdx.x;
    if (g >= NGATES) return;
    const int p = g * 3;
    float s0 = sinf(qw[p+0] * 0.5f), c0 = cosf(qw[p+0] * 0.5f);
    float s1 = sinf(qw[p+1] * 0.5f), c1 = cosf(qw[p+1] * 0.5f);
    float s2 = sinf(qw[p+2] * 0.5f), c2 = cosf(qw[p+2] * 0.5f);
    // M = RY(t1)*RX(t0)
    const float m00r =  c1*c0, m00i =  s1*s0;
    const float m01r = -s1*c0, m01i = -c1*s0;
    const float m10r =  s1*c0, m10i = -c1*s0;
    const float m11r =  c1*c0, m11i = -s1*s0;
    // G = RZ(t2)*M : row0 *= (c2 - i s2), row1 *= (c2 + i s2)
    float* o = gates + g*8;
    o[0] = c2*m00r + s2*m00i;  o[1] = c2*m00i - s2*m00r;
    o[2] = c2*m01r + s2*m01i;  o[3] = c2*m01i - s2*m01r;
    o[4] = c2*m10r - s2*m10i;  o[5] = c2*m10i + s2*m10r;
    o[6] = c2*m11r - s2*m11i;  o[7] = c2*m11i + s2*m11r;
}

// --- Kernel 2: one thread = one sample; 64-complex state in VGPRs.
// Gate coefficients: wave-uniform scalar loads (SGPRs), prefetched one gate
// ahead. sched_barrier(0) every 16 pairs bounds the scheduler's live-range
// window (round 3: unbounded interleave spilled ~650 B/thread). ---
__global__ __launch_bounds__(256) void qnn_fused_kernel(
    const float* __restrict__ x,
    const float* __restrict__ pre_w1, const float* __restrict__ pre_b1,
    const float* __restrict__ pre_w2, const float* __restrict__ pre_b2,
    const float* __restrict__ gates,
    const float* __restrict__ post_w1, const float* __restrict__ post_b1,
    const float* __restrict__ post_w2, const float* __restrict__ post_b2,
    float* __restrict__ out)
{
    const int tid = blockIdx.x * blockDim.x + threadIdx.x;
    const float4 xv = reinterpret_cast<const float4*>(x)[tid];

    // --- pre-net: h = relu(x @ w1 + b1) ---
    float h[16];
    #pragma unroll
    for (int j = 0; j < 16; ++j) {
        float a = pre_b1[j];
        a = fmaf(xv.x, pre_w1[0*16+j], a);
        a = fmaf(xv.y, pre_w1[1*16+j], a);
        a = fmaf(xv.z, pre_w1[2*16+j], a);
        a = fmaf(xv.w, pre_w1[3*16+j], a);
        h[j] = fmaxf(a, 0.f);
    }

    // --- encoding: product state of H*RY(angle_q)|0> columns (all real) ---
    float re[SDIM], im[SDIM];
    re[0] = 1.f;
    #pragma unroll
    for (int q = 0; q < NQ; ++q) {
        float a = pre_b2[q];
        #pragma unroll
        for (int j = 0; j < 16; ++j) a = fmaf(h[j], pre_w2[j*NQ+q], a);
        const float ang = tanhf(a) * 0.5f;
        const float c = __cosf(ang), s = __sinf(ang);
        const float v0 = (c - s) * 0.70710678118654752440f;
        const float v1 = (c + s) * 0.70710678118654752440f;
        #pragma unroll
        for (int i = 0; i < (1 << q); ++i) {
            re[i | (1 << q)] = re[i] * v1;
            re[i] = re[i] * v0;
        }
    }
    __builtin_amdgcn_sched_barrier(0);

    // --- 18 fused variational gates; CX chains are free (index tables) ---
    // Prefetch gate-0 coefficients (uniform -> s_load).
    float c00r = gates[0], c00i = gates[1], c01r = gates[2], c01i = gates[3];
    float c10r = gates[4], c10i = gates[5], c11r = gates[6], c11i = gates[7];

    #pragma unroll
    for (int g = 0; g < NGATES; ++g) {
        const int l = g / NQ, q = g % NQ;
        // prefetch next gate's coefficients before the sched barriers so the
        // s_load latency hides under this gate's FMAs
        float n00r = 0, n00i = 0, n01r = 0, n01i = 0;
        float n10r = 0, n10i = 0, n11r = 0, n11i = 0;
        if (g + 1 < NGATES) {
            const float* np = gates + (g + 1) * 8;
            n00r = np[0]; n00i = np[1]; n01r = np[2]; n01i = np[3];
            n10r = np[4]; n10i = np[5]; n11r = np[6]; n11i = np[7];
        }
        #pragma unroll
        for (int half = 0; half < 2; ++half) {
            #pragma unroll
            for (int k = 0; k < 16; ++k) {
                const int idx = half * 16 + k;                    // pair 0..31
                const int i0 = ((idx >> q) << (q + 1)) | (idx & ((1 << q) - 1));
                const int i1 = i0 | (1 << q);
                const int rA = PERM_TAB[l].p[i0];
                const int rB = PERM_TAB[l].p[i1];
                if (g == 0) {
                    // state still purely real: half the FMAs, and this gate
                    // initializes im[] (no 64-mov zero-init needed)
                    const float r0 = re[rA], r1 = re[rB];
                    re[rA] = c00r*r0 + c01r*r1;
                    im[rA] = c00i*r0 + c01i*r1;
                    re[rB] = c10r*r0 + c11r*r1;
                    im[rB] = c10i*r0 + c11i*r1;
                } else {
                    const float r0 = re[rA], u0 = im[rA];
                    const float r1 = re[rB], u1 = im[rB];
                    re[rA] = c00r*r0 - c00i*u0 + c01r*r1 - c01i*u1;
                    im[rA] = c00r*u0 + c00i*r0 + c01r*u1 + c01i*r1;
                    re[rB] = c10r*r0 - c10i*u0 + c11r*r1 - c11i*u1;
                    im[rB] = c10r*u0 + c10i*r0 + c11r*u1 + c11i*r1;
                }
            }
            __builtin_amdgcn_sched_barrier(0);
        }
        c00r = n00r; c00i = n00i; c01r = n01r; c01i = n01i;
        c10r = n10r; c10i = n10i; c11r = n11r; c11i = n11i;
    }

    // --- probabilities (register order; basis order not needed here) ---
    #pragma unroll
    for (int i = 0; i < SDIM; ++i) re[i] = fmaf(re[i], re[i], im[i]*im[i]);
    __builtin_amdgcn_sched_barrier(0);

    // --- per-qubit Z expectations: basis i lives at register PERM_TAB[2].p[i]
    float ex[NQ];
    #pragma unroll
    for (int q = 0; q < NQ; ++q) {
        float acc = 0.f;
        #pragma unroll
        for (int i = 0; i < SDIM; ++i) {
            const float pv = re[PERM_TAB[NLAYERS-1].p[i]];
            acc = ((i >> q) & 1) ? (acc - pv) : (acc + pv);
        }
        ex[q] = acc;
    }

    // --- post-net ---
    float h2[16];
    #pragma unroll
    for (int j = 0; j < 16; ++j) {
        float a = post_b1[j];
        #pragma unroll
        for (int q = 0; q < NQ; ++q) a = fmaf(ex[q], post_w1[q*16+j], a);
        h2[j] = fmaxf(a, 0.f);
    }
    float o0 = post_b2[0], o1 = post_b2[1], o2 = post_b2[2], o3 = post_b2[3];
    #pragma unroll
    for (int j = 0; j < 16; ++j) {
        o0 = fmaf(h2[j], post_w2[j*4+0], o0);
        o1 = fmaf(h2[j], post_w2[j*4+1], o1);
        o2 = fmaf(h2[j], post_w2[j*4+2], o2);
        o3 = fmaf(h2[j], post_w2[j*4+3], o3);
    }
    reinterpret_cast<float4*>(out)[tid] = make_float4(o0, o1, o2, o3);
}

extern "C" void kernel_launch(void* const* d_in, const int* in_sizes, int n_in,
                              void* d_out, int out_size, void* d_ws, size_t ws_size,
                              hipStream_t stream) {
    const float* x       = (const float*)d_in[0];
    const float* pre_w1  = (const float*)d_in[1];
    const float* pre_b1  = (const float*)d_in[2];
    const float* pre_w2  = (const float*)d_in[3];
    const float* pre_b2  = (const float*)d_in[4];
    const float* qw      = (const float*)d_in[5];
    const float* post_w1 = (const float*)d_in[6];
    const float* post_b1 = (const float*)d_in[7];
    const float* post_w2 = (const float*)d_in[8];
    const float* post_b2 = (const float*)d_in[9];
    float* out   = (float*)d_out;
    float* gates = (float*)d_ws;   // 18*8 floats = 576 B

    gate_prep_kernel<<<1, 64, 0, stream>>>(qw, gates);

    const int block = 256;
    const int grid = QBATCH / block;  // 1024
    qnn_fused_kernel<<<grid, block, 0, stream>>>(
        x, pre_w1, pre_b1, pre_w2, pre_b2, gates,
        post_w1, post_b1, post_w2, post_b2, out);
}